// Round 17
// baseline (145.088 us; speedup 1.0000x reference)
//
#include <hip/hip_runtime.h>

// Problem constants
constexpr int kB  = 8;
constexpr int kT  = 2048;
constexpr int kG  = 1024;
constexpr int kNN = 600;
constexpr int kNE = 424;
constexpr int kD  = 1024;
constexpr int kL  = 2;
constexpr int kBNN = kB * kNN;   // 4800
constexpr int kBNE = kB * kNE;   // 3392
static_assert(kBNE % 64 == 0, "M tiles exact");

typedef __attribute__((ext_vector_type(4))) float f32x4;
typedef __attribute__((ext_vector_type(16))) float f32x16;
typedef __attribute__((ext_vector_type(8))) short bf16x8;
typedef __attribute__((address_space(1))) const void gas_t;
typedef __attribute__((address_space(3))) void las_t;

__device__ __forceinline__ unsigned short f2bf(float x) {
    union { float f; unsigned u; } v; v.f = x;
    unsigned r = v.u + 0x7FFF + ((v.u >> 16) & 1);
    return (unsigned short)(r >> 16);
}

__device__ __forceinline__ void glds16(const void* g, void* l) {
    __builtin_amdgcn_global_load_lds((gas_t*)g, (las_t*)l, 16, 0, 0);
}

// out-tensor offsets for direct writes
__device__ __forceinline__ size_t edge_out_off(int row) {    // row in [0,kBNE)
    int b = row / kNE, r = row - b * kNE;
    return ((size_t)(b * kG + kNN + r)) * kD;
}
__device__ __forceinline__ size_t node_out_off(int n) {      // n in [0,kBNN)
    int b = n / kNN, g = n - b * kNN;
    return ((size_t)(b * kG + g)) * kD;
}

// XCD-aware tile swizzle (T1, r16: -5%): each XCD gets a contiguous bm chunk.
__device__ __forceinline__ void swz_tile(int bx, int by, int& bn, int& bm) {
    int f = bx + 8 * by;            // [0, 424)
    int xcd = f & 7, i = f >> 3;    // i in [0, 53)
    int nf = xcd * 53 + i;          // per-XCD contiguous range
    bm = nf >> 3;
    bn = nf & 7;
}

// ---------------------------------------------------------------------------
// prep kernel: block < kB*kG -> fused embedding gather + ragged mean pool
//              (bounds via binary search over the sorted group-id row);
//              block >= kB*kG -> W [K][N] fp32 -> Wt [N][K] bf16 transpose.
__global__ __launch_bounds__(256) void prep_kernel(const int* __restrict__ tokens,
                                                   const int* __restrict__ gids,
                                                   const float* __restrict__ emb,
                                                   float* __restrict__ nodes,
                                                   float* __restrict__ edges,
                                                   const float* __restrict__ Wm,
                                                   const float* __restrict__ Wu,
                                                   const float* __restrict__ We,
                                                   unsigned short* __restrict__ Wt) {
    __shared__ float tbuf[32][33];
    int bx = blockIdx.x;
    if (bx < kB * kG) {
        int b = bx >> 10, g = bx & (kG - 1);
        int d = threadIdx.x * 4;
        const int* row = gids + (size_t)b * kT;
        int lo = 0, hi = kT;
        while (lo < hi) { int m = (lo + hi) >> 1; if (row[m] < g) lo = m + 1; else hi = m; }
        int s = lo; hi = kT;
        while (lo < hi) { int m = (lo + hi) >> 1; if (row[m] <= g) lo = m + 1; else hi = m; }
        int e = lo;
        float4 acc = make_float4(0.f, 0.f, 0.f, 0.f);
        for (int t = s; t < e; ++t) {
            int tok = tokens[(size_t)b * kT + t];
            const float4 v = *(const float4*)(emb + (size_t)tok * kD + d);
            acc.x += v.x; acc.y += v.y; acc.z += v.z; acc.w += v.w;
        }
        int c = e - s;
        float sc = 1.0f / (float)(c > 0 ? c : 1);
        acc.x *= sc; acc.y *= sc; acc.z *= sc; acc.w *= sc;
        float* dstp = (g < kNN)
            ? (nodes + (size_t)(b * kNN + g) * kD + d)
            : (edges + (size_t)(b * kNE + (g - kNN)) * kD + d);
        *(float4*)dstp = acc;
    } else {
        int idx = bx - kB * kG;             // [0, 6*1024)
        int z = idx >> 10;
        int rem = idx & 1023;
        int n0 = (rem & 31) * 32, k0 = (rem >> 5) * 32;
        const float* W = (z < 2) ? (Wm + (size_t)z * kD * kD)
                       : (z < 4) ? (Wu + (size_t)(z - 2) * kD * kD)
                                 : (We + (size_t)(z - 4) * kD * kD);
        unsigned short* outp = Wt + (size_t)z * kD * kD;
        int r = threadIdx.x >> 3, c4 = (threadIdx.x & 7) * 4;
        const float4 v = *(const float4*)(W + (size_t)(k0 + r) * kD + n0 + c4);
        tbuf[r][c4] = v.x; tbuf[r][c4 + 1] = v.y; tbuf[r][c4 + 2] = v.z; tbuf[r][c4 + 3] = v.w;
        __syncthreads();
        ushort4 o;
        o.x = f2bf(tbuf[c4 + 0][r]); o.y = f2bf(tbuf[c4 + 1][r]);
        o.z = f2bf(tbuf[c4 + 2][r]); o.w = f2bf(tbuf[c4 + 3][r]);
        *(ushort4*)(outp + (size_t)(n0 + r) * kD + k0 + c4) = o;
    }
}

// ---------------------------------------------------------------------------
// gather (+ optional node->out copy folded in, for L1)
template <int COPY>
__global__ void gather_kernel(const float* __restrict__ nodes,
                              const float* __restrict__ edges,
                              const int* __restrict__ src,
                              const int* __restrict__ dst,
                              unsigned short* __restrict__ bufM,
                              unsigned short* __restrict__ bufE,
                              float* __restrict__ out) {
    int d = threadIdx.x * 4;
    int e = blockIdx.x;
    if (COPY && e >= kBNE) {
        int n = e - kBNE;
        *(float4*)(out + node_out_off(n) + d) =
            *(const float4*)(nodes + (size_t)n * kD + d);
        return;
    }
    int s = src[e], t = dst[e];
    const float4 a = *(const float4*)(nodes + (size_t)s * kD + d);
    const float4 b = *(const float4*)(edges + (size_t)e * kD + d);
    const float4 c = *(const float4*)(nodes + (size_t)t * kD + d);
    ushort4 om, oe;
    om.x = f2bf(a.x + b.x); om.y = f2bf(a.y + b.y);
    om.z = f2bf(a.z + b.z); om.w = f2bf(a.w + b.w);
    oe.x = f2bf(a.x + c.x); oe.y = f2bf(a.y + c.y);
    oe.z = f2bf(a.z + c.z); oe.w = f2bf(a.w + c.w);
    *(ushort4*)(bufM + (size_t)e * kD + d) = om;
    *(ushort4*)(bufE + (size_t)e * kD + d) = oe;
}

// ---------------------------------------------------------------------------
// bf16 MFMA GEMM core. A [M][1024] bf16, Wt [N][K] bf16 (B^T layout).
// 64x128 tile, BK=64, 4 waves (2x2 over 32x64 sub-tiles), now 32x32x16 MFMA:
// 8 MFMA/step/wave (was 16) at the higher 32x32 rate -> ~18% less issue time,
// same LDS bytes / ds_read count / 32-VGPR accumulator.
// 3-buffer ring, counted vmcnt, ONE barrier per K-step (r12/r16 schedule):
//   [vmcnt(6)][bar][stage(t+2 -> buf[(t+2)%3])][ds_read][lgkm0][MFMA]
// LDS layout per buffer: A [64 rows][8 chunks][16B] (8KB) + B [128][8][16B]
// (16KB); chunk position p holds source k-chunk p ^ (row&7) (conflict-free).
// A-frag (32x32x16): lane l -> row l&31, k (l>>5)*8+m; B mirrors with col.
// C/D: col=lane&31, row=(reg&3)+8*(reg>>2)+4*(lane>>5)  [m74/m101 verified].
// MODE 0: Cb[row][col] = bf16(relu(acc))                     (msg GEMM)
// MODE 1: Cf[row][col] += acc          (edge GEMM L0; unique rows)
// MODE 2: Of[edge_out_off(row)+col] = Ef[row][col] + acc     (edge GEMM L1)
// MODE 3: atomicAdd(Cf[idxp[row]][col], acc)                 (update L0)
// MODE 4: atomicAdd(Of[node_out_off(idxp[row])+col], acc)    (update L1)
template <int MODE>
__device__ __forceinline__ void gemm_body(const unsigned short* __restrict__ A,
                                          const unsigned short* __restrict__ Wt,
                                          float* __restrict__ Cf,
                                          unsigned short* __restrict__ Cb,
                                          const float* __restrict__ Ef,
                                          const int* __restrict__ idxp,
                                          char* smem, int bn, int bm) {
    const int tid = threadIdx.x;
    const int lane = tid & 63;
    const int w = tid >> 6;
    const int wr = w >> 1, wc = w & 1;
    const int row0 = bm * 64, col0 = bn * 128;
    const int l31 = lane & 31, kh = lane >> 5;     // 32x32 fragment coords

    // staging: lane l covers slab-row (l>>3), chunk-position (l&7) of each
    // 8-row slab; source chunk = (l&7) ^ (l>>3) implements the XOR layout.
    const int sl8 = lane >> 3;                 // 0..7
    const int sc  = (lane & 7) ^ sl8;          // source k-chunk (16B units)
    const unsigned short* agp[2];
    const unsigned short* bgp[4];
#pragma unroll
    for (int q = 0; q < 2; ++q)
        agp[q] = A + (size_t)(row0 + (w * 2 + q) * 8 + sl8) * kD + sc * 8;
#pragma unroll
    for (int q = 0; q < 4; ++q)
        bgp[q] = Wt + (size_t)(col0 + (w * 4 + q) * 8 + sl8) * kD + sc * 8;
    auto stage = [&](int bsel, int k0) {
        char* base = smem + bsel * 24576;
#pragma unroll
        for (int q = 0; q < 2; ++q)
            glds16(agp[q] + k0, base + (w * 2 + q) * 1024);          // A slabs
#pragma unroll
        for (int q = 0; q < 4; ++q)
            glds16(bgp[q] + k0, base + 8192 + (w * 4 + q) * 1024);   // B slabs
    };

    constexpr int nt = kD / 64;                 // 16
    stage(0, 0);
    stage(1, 64);

    f32x16 acc[2] = {};                          // j = 0,1 (two 32x32 tiles)
    int cur = 0;
    for (int t = 0; t < nt; ++t) {
        char* bufc = smem + cur * 24576;
        if (t < nt - 1) asm volatile("s_waitcnt vmcnt(6)" ::: "memory");
        else            asm volatile("s_waitcnt vmcnt(0)" ::: "memory");
        __builtin_amdgcn_s_barrier();           // buf[cur] staged; all reads of
                                                // buf[(cur+2)%3] drained (lgkm0)
        if (t + 2 < nt) stage((cur + 2) % 3, (t + 2) * 64);
        bf16x8 af[4], bf[4][2];
        const int ar = wr * 32 + l31;
        const int bc0 = wc * 64 + l31;
#pragma unroll
        for (int kc = 0; kc < 4; ++kc) {
            int p = ((kc << 1) | kh) ^ (ar & 7);
            af[kc] = *(const bf16x8*)(bufc + ar * 128 + p * 16);
#pragma unroll
            for (int j = 0; j < 2; ++j) {
                int bcol = bc0 + j * 32;
                int pb = ((kc << 1) | kh) ^ (bcol & 7);
                bf[kc][j] = *(const bf16x8*)(bufc + 8192 + bcol * 128 + pb * 16);
            }
        }
        asm volatile("s_waitcnt lgkmcnt(0)" ::: "memory");  // my reads drained
#pragma unroll
        for (int kc = 0; kc < 4; ++kc)
#pragma unroll
            for (int j = 0; j < 2; ++j)
                acc[j] = __builtin_amdgcn_mfma_f32_32x32x16_bf16(
                    af[kc], bf[kc][j], acc[j], 0, 0, 0);
        cur = (cur == 2) ? 0 : cur + 1;
    }
    // epilogue: 32x32 C/D layout col=lane&31, row=(reg&3)+8*(reg>>2)+4*(lane>>5)
#pragma unroll
    for (int j = 0; j < 2; ++j) {
        int col = col0 + wc * 64 + j * 32 + l31;
#pragma unroll
        for (int reg = 0; reg < 16; ++reg) {
            int row = row0 + wr * 32 + (reg & 3) + 8 * (reg >> 2) + 4 * kh;
            float v = acc[j][reg];
            if (MODE == 0) {
                Cb[(size_t)row * kD + col] = f2bf(fmaxf(v, 0.f));
            } else if (MODE == 1) {
                Cf[(size_t)row * kD + col] += v;
            } else if (MODE == 2) {
                Cf[edge_out_off(row) + col] = Ef[(size_t)row * kD + col] + v;
            } else if (MODE == 3) {
                atomicAdd(Cf + (size_t)idxp[row] * kD + col, v);
            } else {
                atomicAdd(Cf + node_out_off(idxp[row]) + col, v);
            }
        }
    }
}

// L0: z=0 msgb = bf16(relu(bufM @ WtM^T));  z=1 edges += bufE @ WtE^T
__global__ __launch_bounds__(256) void gemm_dual_l0(const unsigned short* __restrict__ A0,
                                                    const unsigned short* __restrict__ B0,
                                                    unsigned short* __restrict__ C0,
                                                    const unsigned short* __restrict__ A1,
                                                    const unsigned short* __restrict__ B1,
                                                    float* __restrict__ C1) {
    __shared__ char smem[73728];
    int bn, bm; swz_tile(blockIdx.x, blockIdx.y, bn, bm);
    if (blockIdx.z == 0)
        gemm_body<0>(A0, B0, nullptr, C0, nullptr, nullptr, smem, bn, bm);
    else
        gemm_body<1>(A1, B1, C1, nullptr, nullptr, nullptr, smem, bn, bm);
}

// L1: z=0 msgb = bf16(relu(bufM @ WtM^T));  z=1 out_edges = edges + bufE @ WtE^T
__global__ __launch_bounds__(256) void gemm_dual_l1(const unsigned short* __restrict__ A0,
                                                    const unsigned short* __restrict__ B0,
                                                    unsigned short* __restrict__ C0,
                                                    const unsigned short* __restrict__ A1,
                                                    const unsigned short* __restrict__ B1,
                                                    float* __restrict__ outp,
                                                    const float* __restrict__ edges) {
    __shared__ char smem[73728];
    int bn, bm; swz_tile(blockIdx.x, blockIdx.y, bn, bm);
    if (blockIdx.z == 0)
        gemm_body<0>(A0, B0, nullptr, C0, nullptr, nullptr, smem, bn, bm);
    else
        gemm_body<2>(A1, B1, outp, nullptr, edges, nullptr, smem, bn, bm);
}

// nodes[dst[row]] += (msgb @ WtU^T)[row]   (full K, one atomic per element)
__global__ __launch_bounds__(256) void gemm_upd_l0(const unsigned short* __restrict__ A,
                                                   const unsigned short* __restrict__ B,
                                                   float* __restrict__ C,
                                                   const int* __restrict__ dstIdx) {
    __shared__ char smem[73728];
    int bn, bm; swz_tile(blockIdx.x, blockIdx.y, bn, bm);
    gemm_body<3>(A, B, C, nullptr, nullptr, dstIdx, smem, bn, bm);
}

// out_nodes[dst[row]] += (msgb @ WtU^T)[row]  (final layer -> d_out directly)
__global__ __launch_bounds__(256) void gemm_upd_l1(const unsigned short* __restrict__ A,
                                                   const unsigned short* __restrict__ B,
                                                   float* __restrict__ outp,
                                                   const int* __restrict__ dstIdx) {
    __shared__ char smem[73728];
    int bn, bm; swz_tile(blockIdx.x, blockIdx.y, bn, bm);
    gemm_body<4>(A, B, outp, nullptr, nullptr, dstIdx, smem, bn, bm);
}

// ---------------------------------------------------------------------------
extern "C" void kernel_launch(void* const* d_in, const int* in_sizes, int n_in,
                              void* d_out, int out_size, void* d_ws, size_t ws_size,
                              hipStream_t stream) {
    const int*   tokens = (const int*)d_in[0];
    const int*   gids   = (const int*)d_in[1];
    const int*   eidx   = (const int*)d_in[3];
    const float* emb    = (const float*)d_in[4];
    const float* Wm     = (const float*)d_in[5];
    const float* Wu     = (const float*)d_in[6];
    const float* We     = (const float*)d_in[7];
    float* out = (float*)d_out;

    // workspace layout
    constexpr size_t szNodes = (size_t)kBNN * kD * 4;   // fp32 master
    constexpr size_t szEdges = (size_t)kBNE * kD * 4;   // fp32 master
    constexpr size_t szBufM  = (size_t)kBNE * kD * 2;   // bf16
    constexpr size_t szBufE  = (size_t)kBNE * kD * 2;   // bf16
    constexpr size_t szMsgB  = (size_t)kBNE * kD * 2;   // bf16
    char* ws = (char*)d_ws;
    float*          nodes = (float*)ws;
    float*          edges = (float*)(ws + szNodes);
    unsigned short* bufM  = (unsigned short*)(ws + szNodes + szEdges);
    unsigned short* bufE  = (unsigned short*)(ws + szNodes + szEdges + szBufM);
    unsigned short* msgb  = (unsigned short*)(ws + szNodes + szEdges + szBufM + szBufE);
    unsigned short* Wt    = (unsigned short*)(ws + szNodes + szEdges + szBufM + szBufE + szMsgB);

    const int* srcIdx = eidx;
    const int* dstIdx = eidx + kBNE;
    unsigned short* WtM = Wt;                           // [l][N][K]
    unsigned short* WtU = Wt + (size_t)2 * kD * kD;
    unsigned short* WtE = Wt + (size_t)4 * kD * kD;

    // pool (binary-search bounds) + weight transpose, one launch
    prep_kernel<<<kB * kG + 6 * 1024, 256, 0, stream>>>(
        tokens, gids, emb, nodes, edges, Wm, Wu, We, Wt);

    constexpr int mt = kBNE / 64;                // 53
    const dim3 gdual(kD / 128, mt, 2);           // 848 blocks
    const dim3 gupd(kD / 128, mt, 1);            // 424 blocks, full K

    // ---- layer 0 ----
    gather_kernel<0><<<kBNE, 256, 0, stream>>>(nodes, edges, srcIdx, dstIdx, bufM, bufE, out);
    gemm_dual_l0<<<gdual, 256, 0, stream>>>(bufM, WtM, msgb, bufE, WtE, edges);
    gemm_upd_l0<<<gupd, 256, 0, stream>>>(msgb, WtU, nodes, dstIdx);

    // ---- layer 1 (writes final values straight into d_out) ----
    gather_kernel<1><<<kBNE + kBNN, 256, 0, stream>>>(nodes, edges, srcIdx, dstIdx, bufM, bufE, out);
    gemm_dual_l1<<<gdual, 256, 0, stream>>>(bufM, WtM + (size_t)kD * kD, msgb,
                                            bufE, WtE + (size_t)kD * kD, out, edges);
    gemm_upd_l1<<<gupd, 256, 0, stream>>>(msgb, WtU + (size_t)kD * kD, out, dstIdx);
}